// Round 10
// baseline (11895.627 us; speedup 1.0000x reference)
//
#include <hip/hip_runtime.h>
#include <cmath>

// ---------------------------------------------------------------------------
// Graves handwriting synthesis: 3-layer GRU + attention window + MDN head
// B=32 T=512 U=64 V=60 H=400 K=10 M=20 IN=3
//
// Round 14 (resubmit; r9 GPU acquisition timed out): halve the sync
// population. Merge (slice,bhalf) pairs into one 512-thread block (75
// blocks, 8 waves): each block covers all 32 samples for its 16-unit slice.
// Flag protocol / ring layout / wait graph IDENTICAL to r13 (3 groups x 25
// slice flags; targets t / t+1 / t-3).
//  - polling waves 450 -> 225, straggler population per edge 50 -> 25
//  - one staging pass for 32 samples (same per-thread load count)
//  - attention: p-MFMA on waves {0,1,4,5} (2 rowtiles x 2 sample halves);
//    wave-local softmax 4 samples/wave x 8 waves
//  - LDS 132KB/block (under 160KB; 1 block/CU is all we need at 75 blocks)
//  r13 kept: batched staging issue, wave-local attention, post-flag feature
//  stores, 3-acc MFMA chains, LDS-atomic w-scatter, s_sleep backoff.
// ---------------------------------------------------------------------------

typedef __attribute__((ext_vector_type(8))) short bf16x8;
typedef __attribute__((ext_vector_type(4))) float f32x4;
typedef unsigned short ushort_t;

namespace {
constexpr int B_ = 32, T_ = 512, U_ = 64, V_ = 60, H_ = 400, K_ = 10, M_ = 20;
constexpr int N_ = B_ * T_;          // 16384
constexpr int SEG = 416, FEAT_LD = 1248;
constexpr int NBLK = 75;             // 3 groups x 25 slices
constexpr int SBL = 872;             // B-row stride in LDS (u16), 16B-aligned

// workspace layout (float indices)
constexpr size_t OFF_R0    = 0;                       // 4*32*400 u32 per ring
constexpr size_t OFF_R1    = 51200;
constexpr size_t OFF_R2    = 102400;
constexpr size_t OFF_WRING = 153600;                  // 4*32*60 f32
constexpr size_t OFF_BAR   = 161280;                  // 1088 uints
constexpr size_t ZERO_TOT  = OFF_BAR + 1088;
constexpr size_t OFF_FEATH = ZERO_TOT;                // N*1248 bf16
constexpr size_t OFF_FEATL = OFF_FEATH + (size_t)N_ * FEAT_LD / 2;
constexpr size_t OFF_WHH   = OFF_FEATL + (size_t)N_ * FEAT_LD / 2;  // 128*1248 bf16
constexpr size_t OFF_WHL   = OFF_WHH + (size_t)128 * FEAT_LD / 2;
constexpr size_t OFF_P     = OFF_WHL + (size_t)128 * FEAT_LD / 2;   // N*128 f32

// bar layout (uints): flags for group g (= L) at [128 + 64*g + s], s=0..24.
constexpr int BAR_FLAGS = 128;

// d_out layout (floats), reference return order
constexpr int DO_MEANS = 0;
constexpr int DO_STD   = B_ * T_ * M_ * 2;
constexpr int DO_LOGW  = DO_STD + B_ * T_ * M_;
constexpr int DO_CORR  = DO_LOGW + B_ * T_ * M_;
constexpr int DO_LAST  = DO_CORR + B_ * T_ * M_;
constexpr int DO_PHI   = DO_LAST + B_ * T_;
} // namespace

// ---------------------------------------------------------------------------
__device__ __forceinline__ float load_agent(const float* p) {
  return __hip_atomic_load(p, __ATOMIC_RELAXED, __HIP_MEMORY_SCOPE_AGENT);
}
__device__ __forceinline__ void store_agent(float* p, float v) {
  __hip_atomic_store(p, v, __ATOMIC_RELAXED, __HIP_MEMORY_SCOPE_AGENT);
}
__device__ __forceinline__ void store_agent_u32(unsigned* p, unsigned v) {
  __hip_atomic_store(p, v, __ATOMIC_RELAXED, __HIP_MEMORY_SCOPE_AGENT);
}
__device__ __forceinline__ unsigned load_agent_u32(const unsigned* p) {
  return __hip_atomic_load(p, __ATOMIC_RELAXED, __HIP_MEMORY_SCOPE_AGENT);
}
__device__ __forceinline__ unsigned long long load_agent_u64(const unsigned long long* p) {
  return __hip_atomic_load(p, __ATOMIC_RELAXED, __HIP_MEMORY_SCOPE_AGENT);
}
__device__ __forceinline__ ushort_t f2bf(float f) {
  union { float f; unsigned u; } x{f};
  unsigned r = x.u + 0x7FFFu + ((x.u >> 16) & 1u);
  return (ushort_t)(r >> 16);
}
__device__ __forceinline__ void split2(float f, ushort_t& h, ushort_t& l) {
  h = f2bf(f);
  union { unsigned u; float f; } c;
  c.u = ((unsigned)h) << 16;
  l = f2bf(f - c.f);
}
__device__ __forceinline__ float bfpair(ushort_t h, ushort_t l) {
  union { unsigned u; float f; } a, b;
  a.u = ((unsigned)h) << 16; b.u = ((unsigned)l) << 16;
  return a.f + b.f;
}
__device__ __forceinline__ float sigmoidf_(float x) {
  return 1.f / (1.f + __expf(-x));
}

// wave-parallel poll: lane i watches flags[i] (i<nf) until >= target.
__device__ __forceinline__ void wave_poll(const unsigned* flags, int nf, int target) {
  if (target <= 0) return;
  const int lane = threadIdx.x & 63;
  const unsigned* p = flags + (lane < nf ? lane : 0);
  int spins = 0;
  for (;;) {
    int v = (int)load_agent_u32(p);
    if (__all(lane >= nf || v >= target)) break;
    if (++spins > 3) __builtin_amdgcn_s_sleep(8);
    else             __builtin_amdgcn_s_sleep(1);
  }
}

// ---------------------------------------------------------------------------
// Staging of one packed-ring 32x400 region (12800 u32 = 6400 u64) with 512
// threads: issue (loads into regs, all in flight) + write (unpack -> LDS).
__device__ __forceinline__ void stage_issue(const unsigned* __restrict__ src,
                                            unsigned long long* v) {
  const int tid = threadIdx.x;
#pragma unroll
  for (int i = 0; i < 12; ++i)
    v[i] = load_agent_u64((const unsigned long long*)(src + (tid + i * 512) * 2));
  if (tid < 256)
    v[12] = load_agent_u64((const unsigned long long*)(src + (6144 + tid) * 2));
}
__device__ __forceinline__ void stage_write(const unsigned long long* v,
                                            ushort_t* __restrict__ BhB,
                                            ushort_t* __restrict__ BlB, int koff) {
  const int tid = threadIdx.x;
#pragma unroll
  for (int i = 0; i < 12; ++i) {
    int e = (tid + i * 512) * 2;
    int b = e / 400, k = e - b * 400;
    unsigned p0 = (unsigned)v[i], p1 = (unsigned)(v[i] >> 32);
    *(unsigned*)(BhB + b * SBL + koff + k) = (p0 >> 16) | (p1 & 0xFFFF0000u);
    *(unsigned*)(BlB + b * SBL + koff + k) = (p0 & 0xFFFFu) | (p1 << 16);
  }
  if (tid < 256) {
    int e = (6144 + tid) * 2;
    int b = e / 400, k = e - b * 400;
    unsigned p0 = (unsigned)v[12], p1 = (unsigned)(v[12] >> 32);
    *(unsigned*)(BhB + b * SBL + koff + k) = (p0 >> 16) | (p1 & 0xFFFF0000u);
    *(unsigned*)(BlB + b * SBL + koff + k) = (p0 & 0xFFFFu) | (p1 << 16);
  }
}

// ---------------------------------------------------------------------------
__global__ __launch_bounds__(256)
void zero_ws(float* __restrict__ p) {
  size_t i = (size_t)blockIdx.x * 256 + threadIdx.x;
  if (i < ZERO_TOT) p[i] = 0.f;
}

__global__ void zero_feat_pads(ushort_t* __restrict__ fh, ushort_t* __restrict__ fl) {
  int idx = blockIdx.x * 256 + threadIdx.x;
  if (idx >= N_ * 48) return;
  int n = idx / 48, r = idx % 48;
  size_t o = (size_t)n * FEAT_LD + (r / 16) * SEG + 400 + (r % 16);
  fh[o] = 0; fl[o] = 0;
}

__global__ void split_wh_kernel(const float* __restrict__ Wh,
                                ushort_t* __restrict__ hi, ushort_t* __restrict__ lo) {
  int idx = blockIdx.x * 256 + threadIdx.x;
  if (idx >= 128 * FEAT_LD) return;
  int m = idx / FEAT_LD, k = idx % FEAT_LD;
  int seg = k / SEG, off = k % SEG;
  float v = (m < 121 && off < 400) ? Wh[(size_t)m * 1200 + seg * 400 + off] : 0.f;
  ushort_t h, l; split2(v, h, l);
  hi[idx] = h; lo[idx] = l;
}

__global__ __launch_bounds__(256)
void gemm_split_kernel(const ushort_t* __restrict__ Ahi, const ushort_t* __restrict__ Alo,
                       const ushort_t* __restrict__ Bhi, const ushort_t* __restrict__ Blo,
                       const float* __restrict__ bias, float* __restrict__ C,
                       int mtiles, int ntiles, int ktiles, int strideA, int strideB,
                       int Mvalid, int ldc) {
  int wave = blockIdx.x * 4 + (threadIdx.x >> 6);
  if (wave >= mtiles * ntiles) return;
  int mt = wave / ntiles, nt = wave % ntiles;
  int lane = threadIdx.x & 63, l15 = lane & 15, quad = lane >> 4;
  size_t aoff = (size_t)(mt * 16 + l15) * strideA + quad * 8;
  size_t boff = (size_t)(nt * 16 + l15) * strideB + quad * 8;
  f32x4 a0 = {0.f, 0.f, 0.f, 0.f}, a1 = a0, a2 = a0;
  for (int kt = 0; kt < ktiles; ++kt) {
    bf16x8 ah = *(const bf16x8*)(Ahi + aoff + kt * 32);
    bf16x8 al = *(const bf16x8*)(Alo + aoff + kt * 32);
    bf16x8 bh = *(const bf16x8*)(Bhi + boff + kt * 32);
    bf16x8 bl = *(const bf16x8*)(Blo + boff + kt * 32);
    a0 = __builtin_amdgcn_mfma_f32_16x16x32_bf16(ah, bh, a0, 0, 0, 0);
    a1 = __builtin_amdgcn_mfma_f32_16x16x32_bf16(ah, bl, a1, 0, 0, 0);
    a2 = __builtin_amdgcn_mfma_f32_16x16x32_bf16(al, bh, a2, 0, 0, 0);
  }
  int n = nt * 16 + l15;
#pragma unroll
  for (int r = 0; r < 4; ++r) {
    int m = mt * 16 + quad * 4 + r;
    if (m < Mvalid) C[(size_t)n * ldc + m] = a0[r] + a1[r] + a2[r] + bias[m];
  }
}

// ---------------------------------------------------------------------------
// fused pipelined scan body (templated per layer); 512-thread blocks,
// block covers all 32 samples for its 16-unit slice.
template <int L>
__device__ __forceinline__ void scan_body(
    int slice,
    const float* __restrict__ x, const int* __restrict__ c,
    const float* __restrict__ Wih, const float* __restrict__ Whh,
    const float* __restrict__ bih, const float* __restrict__ bhh,
    const float* __restrict__ Ww, const float* __restrict__ bw,
    unsigned* __restrict__ ringS, const unsigned* __restrict__ ringP,
    const float* __restrict__ wring_c, float* __restrict__ wring_w,
    ushort_t* __restrict__ fh, ushort_t* __restrict__ fl,
    float* __restrict__ out_phi, unsigned* __restrict__ bar,
    ushort_t* Bh, ushort_t* Bl, float (*su)[65], float (*sp)[33],
    float (*skap)[10], unsigned char (*sc)[64], float (*sw)[60]) {
  constexpr int KT = (L == 0) ? 15 : 27;
  constexpr int CONST_K = (L == 0) ? 463 : 863;
  constexpr int XOFF = (L == 0) ? 460 : 860;
  constexpr int WOFF = (L == 0) ? 400 : 800;
  constexpr int IW = (L == 0) ? 63 : 463;
  const int tid = threadIdx.x;
  const int waveid = tid >> 6, lane = tid & 63;
  const int l15 = lane & 15, quad = lane >> 4;
  const int rt = waveid & 3;             // rowtile 0..3
  const int sh = waveid >> 2;            // sample half 0/1
  const int uu = l15 & 3, gate = l15 >> 2;   // 0=r 1=z 2=hn 3=inn
  const int J = slice * 16 + rt * 4 + uu;

  // flag plumbing: own / parent / child flag arrays (one group per layer)
  unsigned* fOwn    = bar + BAR_FLAGS + 64 * L;
  unsigned* fParent = (L >= 1) ? bar + BAR_FLAGS + 64 * (L - 1) : nullptr;
  unsigned* fChild  = (L <= 1) ? bar + BAR_FLAGS + 64 * (L + 1) : nullptr;

  // ---- main A-fragments (split bf16), in registers for all 512 steps ----
  bf16x8 afh[KT], afl[KT];
#pragma unroll
  for (int kt = 0; kt < KT; ++kt) {
    union { bf16x8 v; ushort_t s[8]; } uh, ul;
#pragma unroll
    for (int j = 0; j < 8; ++j) {
      int k = kt * 32 + quad * 8 + j;
      float v = 0.f;
      if (k < 400) {
        if (gate == 0)      v = Whh[(size_t)J * 400 + k];
        else if (gate == 1) v = Whh[(size_t)(400 + J) * 400 + k];
        else if (gate == 2) v = Whh[(size_t)(800 + J) * 400 + k];
      } else if (k < CONST_K) {
        int col;
        if (L == 0) col = (k < 460) ? 3 + (k - 400) : (k - 460);
        else        col = (k < 800) ? 3 + (k - 400)
                        : (k < 860) ? 403 + (k - 800) : (k - 860);
        if (gate == 0)      v = Wih[(size_t)J * IW + col];
        else if (gate == 1) v = Wih[(size_t)(400 + J) * IW + col];
        else if (gate == 3) v = Wih[(size_t)(800 + J) * IW + col];
      } else if (k == CONST_K) {
        if (gate == 0)      v = bih[J] + bhh[J];
        else if (gate == 1) v = bih[400 + J] + bhh[400 + J];
        else if (gate == 2) v = bhh[800 + J];
        else                v = bih[800 + J];
      }
      ushort_t h, l; split2(v, h, l);
      uh.s[j] = h; ul.s[j] = l;
    }
    afh[kt] = uh.v; afl[kt] = ul.v;
  }

  // ---- attention p-fragments: waves {0,1,4,5} own rowtile (waveid&1) ----
  bf16x8 apfh[14], apfl[14];
  if constexpr (L <= 1) {
    const int prow = ((waveid & 3) < 2) ? ((waveid & 1) * 16 + l15) : 32;
#pragma unroll
    for (int pk = 0; pk < 14; ++pk) {
      int kt = (pk < 13) ? ((L == 0) ? pk : 12 + pk) : ((L == 0) ? 14 : 26);
      union { bf16x8 v; ushort_t s[8]; } uh, ul;
#pragma unroll
      for (int j = 0; j < 8; ++j) {
        int k = kt * 32 + quad * 8 + j;
        int col = k - ((L == 0) ? 0 : 400);
        float v = 0.f;
        if (prow < 30) {
          if (col >= 0 && col < 400) v = Ww[prow * 400 + col];
          else if (k == CONST_K)     v = bw[prow];
        }
        ushort_t h, l; split2(v, h, l);
        uh.s[j] = h; ul.s[j] = l;
      }
      apfh[pk] = uh.v; apfl[pk] = ul.v;
    }
  }

  // ---- one-time LDS init ----
  for (int i = tid; i < 32 * SBL; i += 512) { Bh[i] = 0; Bl[i] = 0; }
  for (int i = tid; i < 320; i += 512) skap[i / 10][i % 10] = 0.f;
  if constexpr (L <= 1) {
    for (int i = tid; i < 32 * 64; i += 512)
      sc[i >> 6][i & 63] = (unsigned char)c[(i >> 6) * U_ + (i & 63)];
  }
  __syncthreads();
  if (tid < 32) Bh[tid * SBL + CONST_K] = 0x3F80;  // bf16(1.0); lo stays 0
  __syncthreads();

  // ---- time loop: dataflow sync via wave-parallel flag polls ----
  for (int t = 0; t < T_; ++t) {
    if (waveid == 0)      wave_poll(fOwn, 25, t);             // peers done t-1
    else if (waveid == 1) { if (L >= 1) wave_poll(fParent, 25, t + 1); }
    else if (waveid == 2) { if (L <= 1) wave_poll(fChild, 25, t - 3); }
    __syncthreads();

    // -- staging ISSUE: all rings' loads in flight together --
    unsigned long long vS[13], vP[13];
    float wv[4] = {0.f, 0.f, 0.f, 0.f};
    float xv = 0.f;
    stage_issue(ringS + (size_t)((t + 3) & 3) * 12800, vS);
    if constexpr (L >= 1)
      stage_issue(ringP + (size_t)(t & 3) * 12800, vP);
    if constexpr (L == 2) {
      const float* srcw = wring_c + (size_t)(t & 3) * 1920;
#pragma unroll
      for (int i = 0; i < 3; ++i) wv[i] = load_agent(srcw + tid + i * 512);
      if (tid < 384) wv[3] = load_agent(srcw + 1536 + tid);
    }
    if (tid < 96) xv = x[((size_t)(tid / 3) * T_ + t) * 3 + (tid % 3)];

    // -- staging WRITE (consume in issue order) --
    stage_write(vS, Bh, Bl, 0);
    if constexpr (L >= 1) stage_write(vP, Bh, Bl, 400);
    if constexpr (L == 2) {
#pragma unroll
      for (int i = 0; i < 3; ++i) {
        int idx = tid + i * 512;
        int b = idx / 60, v = idx - b * 60;
        ushort_t h, l; split2(wv[i], h, l);
        Bh[b * SBL + WOFF + v] = h; Bl[b * SBL + WOFF + v] = l;
      }
      if (tid < 384) {
        int idx = 1536 + tid;
        int b = idx / 60, v = idx - b * 60;
        ushort_t h, l; split2(wv[3], h, l);
        Bh[b * SBL + WOFF + v] = h; Bl[b * SBL + WOFF + v] = l;
      }
    }
    if (tid < 96) {
      int b = tid / 3, xc = tid - b * 3;
      ushort_t h, l; split2(xv, h, l);
      Bh[b * SBL + XOFF + xc] = h; Bl[b * SBL + XOFF + xc] = l;
    }
    __syncthreads();

    // -- attention (L0 computes w(t-1) for own input; L1 computes w(t)) --
    if constexpr (L <= 1) {
      const bool dow = (L == 1) || (t > 0);
      if (dow) {
        if ((waveid & 3) < 2) {  // p-MFMA: waves 0,1 (half0) and 4,5 (half1)
          f32x4 a0 = {0.f, 0.f, 0.f, 0.f}, a1 = a0, a2 = a0;
          const int brow = (sh * 16 + l15) * SBL + quad * 8;
#pragma unroll
          for (int pk = 0; pk < 14; ++pk) {
            int kt = (pk < 13) ? ((L == 0) ? pk : 12 + pk) : ((L == 0) ? 14 : 26);
            bf16x8 bh8 = *(const bf16x8*)(Bh + brow + kt * 32);
            bf16x8 bl8 = *(const bf16x8*)(Bl + brow + kt * 32);
            a0 = __builtin_amdgcn_mfma_f32_16x16x32_bf16(apfh[pk], bh8, a0, 0, 0, 0);
            a1 = __builtin_amdgcn_mfma_f32_16x16x32_bf16(apfh[pk], bl8, a1, 0, 0, 0);
            a2 = __builtin_amdgcn_mfma_f32_16x16x32_bf16(apfl[pk], bh8, a2, 0, 0, 0);
          }
#pragma unroll
          for (int r = 0; r < 4; ++r)
            sp[sh * 16 + l15][(waveid & 1) * 16 + quad * 4 + r] = a0[r] + a1[r] + a2[r];
        }
        __syncthreads();
        // ---- wave-local phases: wave owns samples b0..b0+3 ----
        {
          const int b0 = waveid * 4;
          for (int i = lane; i < 120; i += 64) {           // exp(p)
            int b = b0 + i / 30, mm = i % 30;
            sp[b][mm] = __expf(sp[b][mm]);
          }
          if (lane < 40) {                                 // kappa += dk
            int b = b0 + lane / 10, k2 = lane % 10;
            skap[b][k2] += sp[b][20 + k2];
          }
          for (int i = lane; i < 240; i += 64)             // zero w accum
            sw[b0 + i / 60][i % 60] = 0.f;
          for (int i = lane; i < 260; i += 64) {           // phi
            int b = b0 + i / 65, u = i % 65;
            float s = 0.f;
#pragma unroll
            for (int k2 = 0; k2 < 10; ++k2) {
              float d = skap[b][k2] - (float)u;
              s = fmaf(sp[b][k2], __expf(-sp[b][10 + k2] * d * d), s);
            }
            su[b][u] = s;
          }
          for (int i = lane; i < 256; i += 64) {           // scatter phi -> w
            int b = b0 + (i >> 6), u = i & 63;
            atomicAdd(&sw[b][sc[b][u]], su[b][u]);
          }
          for (int i = lane; i < 240; i += 64) {           // write w into B
            int b = b0 + i / 60, v = i % 60;
            float s = sw[b][v];
            ushort_t h, l2; split2(s, h, l2);
            Bh[b * SBL + WOFF + v] = h; Bl[b * SBL + WOFF + v] = l2;
            if (L == 1 && slice == 0)                      // publish w(t) for L2
              store_agent(wring_w + (size_t)(t & 3) * 1920 + b * 60 + v, s);
          }
          if (L == 1 && t == T_ - 1 && slice == 0) {
            for (int i = lane; i < 260; i += 64) {
              int b = b0 + i / 65, u = i % 65;
              out_phi[b * 65 + u] = su[b][u];
            }
          }
        }
        __syncthreads();
      }
    }

    // -- main MFMA: rows = rowtile rt, cols = 16 samples of half sh --
    {
      f32x4 a0 = {0.f, 0.f, 0.f, 0.f}, a1 = a0, a2 = a0;
      const int brow = (sh * 16 + l15) * SBL + quad * 8;
#pragma unroll
      for (int kt = 0; kt < KT; ++kt) {
        bf16x8 bh8 = *(const bf16x8*)(Bh + brow + kt * 32);
        bf16x8 bl8 = *(const bf16x8*)(Bl + brow + kt * 32);
        a0 = __builtin_amdgcn_mfma_f32_16x16x32_bf16(afh[kt], bh8, a0, 0, 0, 0);
        a1 = __builtin_amdgcn_mfma_f32_16x16x32_bf16(afh[kt], bl8, a1, 0, 0, 0);
        a2 = __builtin_amdgcn_mfma_f32_16x16x32_bf16(afl[kt], bh8, a2, 0, 0, 0);
      }
#pragma unroll
      for (int r = 0; r < 4; ++r)
        su[sh * 16 + l15][rt * 16 + quad * 4 + r] = a0[r] + a1[r] + a2[r];
    }
    __syncthreads();

    // -- combine: 512 threads = 32 samples x 16 units (unit fastest) --
    ushort_t hh, hl;
    const int cb = tid >> 4, cu = tid & 15;
    {
      int urt = cu >> 2, u3 = cu & 3;
      float rr = sigmoidf_(su[cb][urt * 16 + 0 * 4 + u3]);
      float zz = sigmoidf_(su[cb][urt * 16 + 1 * 4 + u3]);
      float hn = su[cb][urt * 16 + 2 * 4 + u3];
      float inn = su[cb][urt * 16 + 3 * 4 + u3];
      int Jc = slice * 16 + cu;
      float hold = bfpair(Bh[cb * SBL + Jc], Bl[cb * SBL + Jc]);
      float hv = (1.f - zz) * tanhf(inn + rr * hn) + zz * hold;
      split2(hv, hh, hl);
      store_agent_u32(ringS + (size_t)(t & 3) * 12800 + cb * 400 + Jc,
                      ((unsigned)hh << 16) | (unsigned)hl);
    }

    // -- drain ring/wring stores, publish own flag (t+1) --
    __builtin_amdgcn_s_waitcnt(0);
    __syncthreads();
    if (tid == 0) store_agent_u32(fOwn + slice, (unsigned)(t + 1));

    // -- feature stores AFTER flag (gemm is kernel-boundary ordered) --
    {
      int n = cb * T_ + t;
      size_t fo = (size_t)n * FEAT_LD + L * SEG + (slice * 16 + cu);
      fh[fo] = hh; fl[fo] = hl;
    }
  }
}

__global__ __launch_bounds__(512, 1)
void fused_scan(const float* __restrict__ x, const int* __restrict__ c,
                const float* Wih0, const float* Whh0, const float* bih0, const float* bhh0,
                const float* Wih1, const float* Whh1, const float* bih1, const float* bhh1,
                const float* Wih2, const float* Whh2, const float* bih2, const float* bhh2,
                const float* __restrict__ Ww, const float* __restrict__ bw,
                unsigned* ring0, unsigned* ring1, unsigned* ring2, float* wring,
                ushort_t* __restrict__ fh, ushort_t* __restrict__ fl,
                float* __restrict__ out_phi, unsigned* __restrict__ bar) {
  __shared__ ushort_t Bh[32 * SBL];
  __shared__ ushort_t Bl[32 * SBL];
  __shared__ float su[32][65];     // sdots (64 cols) UNION sphi (65)
  __shared__ float sp[32][33];     // attention p (exp'ed); rows 30,31 unused
  __shared__ float skap[32][10];
  __shared__ unsigned char sc[32][64];
  __shared__ float sw[32][60];     // w scatter accumulator

  const int bx = blockIdx.x;
  const int grpL = bx / 25, slice = bx % 25;

  if (grpL == 0)
    scan_body<0>(slice, x, c, Wih0, Whh0, bih0, bhh0, Ww, bw,
                 ring0, nullptr, nullptr, nullptr, fh, fl, out_phi, bar,
                 Bh, Bl, su, sp, skap, sc, sw);
  else if (grpL == 1)
    scan_body<1>(slice, x, c, Wih1, Whh1, bih1, bhh1, Ww, bw,
                 ring1, ring0, nullptr, wring, fh, fl, out_phi, bar,
                 Bh, Bl, su, sp, skap, sc, sw);
  else
    scan_body<2>(slice, x, c, Wih2, Whh2, bih2, bhh2, Ww, bw,
                 ring2, ring1, wring, nullptr, fh, fl, out_phi, bar,
                 Bh, Bl, su, sp, skap, sc, sw);
}

// ---------------------------------------------------------------------------
__global__ __launch_bounds__(256)
void post_kernel(const float* __restrict__ p, float* __restrict__ dout) {
  int n = blockIdx.x * 256 + threadIdx.x;
  if (n >= N_) return;
  const float* r = p + (size_t)n * 128;
  dout[DO_LAST + n] = r[0];
  float mx = -1e30f;
  for (int m = 0; m < M_; ++m) mx = fmaxf(mx, r[1 + m]);
  float s = 0.f;
  for (int m = 0; m < M_; ++m) s += __expf(r[1 + m] - mx);
  float lse = mx + logf(s);
  for (int m = 0; m < M_; ++m) dout[DO_LOGW + (size_t)n * M_ + m] = r[1 + m] - lse;
  for (int i = 0; i < 2 * M_; ++i) dout[DO_MEANS + (size_t)n * 2 * M_ + i] = r[21 + i];
  for (int m = 0; m < M_; ++m) dout[DO_STD + (size_t)n * M_ + m] = __expf(r[61 + m]);
  for (int m = 0; m < M_; ++m) dout[DO_CORR + (size_t)n * M_ + m] = tanhf(r[81 + m]);
}

// ---------------------------------------------------------------------------
extern "C" void kernel_launch(void* const* d_in, const int* in_sizes, int n_in,
                              void* d_out, int out_size, void* d_ws, size_t ws_size,
                              hipStream_t stream) {
  const float* x    = (const float*)d_in[0];
  const int*   c    = (const int*)d_in[1];
  const float* Wih0 = (const float*)d_in[2];
  const float* Whh0 = (const float*)d_in[3];
  const float* bih0 = (const float*)d_in[4];
  const float* bhh0 = (const float*)d_in[5];
  const float* Wih1 = (const float*)d_in[6];
  const float* Whh1 = (const float*)d_in[7];
  const float* bih1 = (const float*)d_in[8];
  const float* bhh1 = (const float*)d_in[9];
  const float* Wih2 = (const float*)d_in[10];
  const float* Whh2 = (const float*)d_in[11];
  const float* bih2 = (const float*)d_in[12];
  const float* bhh2 = (const float*)d_in[13];
  const float* Ww   = (const float*)d_in[14];
  const float* bw   = (const float*)d_in[15];
  const float* Wh   = (const float*)d_in[16];
  const float* bh   = (const float*)d_in[17];
  (void)in_sizes; (void)n_in; (void)out_size; (void)ws_size;

  float* ws = (float*)d_ws;
  unsigned* ring0 = (unsigned*)(ws + OFF_R0);
  unsigned* ring1 = (unsigned*)(ws + OFF_R1);
  unsigned* ring2 = (unsigned*)(ws + OFF_R2);
  float*    wring = ws + OFF_WRING;
  unsigned* bar   = (unsigned*)(ws + OFF_BAR);
  ushort_t* fh    = (ushort_t*)(ws + OFF_FEATH);
  ushort_t* fl    = (ushort_t*)(ws + OFF_FEATL);
  ushort_t* whh_  = (ushort_t*)(ws + OFF_WHH);
  ushort_t* whl_  = (ushort_t*)(ws + OFF_WHL);
  float*    pbuf  = ws + OFF_P;
  float*    dout  = (float*)d_out;

  const dim3 blk(256);

  zero_ws<<<dim3((int)((ZERO_TOT + 255) / 256)), blk, 0, stream>>>(ws);
  zero_feat_pads<<<dim3((N_ * 48) / 256), blk, 0, stream>>>(fh, fl);
  split_wh_kernel<<<dim3((128 * FEAT_LD) / 256), blk, 0, stream>>>(Wh, whh_, whl_);

  fused_scan<<<dim3(NBLK), dim3(512), 0, stream>>>(
      x, c, Wih0, Whh0, bih0, bhh0, Wih1, Whh1, bih1, bhh1,
      Wih2, Whh2, bih2, bhh2, Ww, bw,
      ring0, ring1, ring2, wring, fh, fl, dout + DO_PHI, bar);

  gemm_split_kernel<<<dim3(8 * (N_ / 16) / 4), blk, 0, stream>>>(
      whh_, whl_, fh, fl, bh, pbuf, 8, N_ / 16, FEAT_LD / 32,
      FEAT_LD, FEAT_LD, 121, 128);
  post_kernel<<<dim3(N_ / 256), blk, 0, stream>>>(pbuf, dout);
}

// Round 14
// 5669.658 us; speedup vs baseline: 2.0981x; 2.0981x over previous
//
#include <hip/hip_runtime.h>
#include <cmath>

// ---------------------------------------------------------------------------
// Graves handwriting synthesis: 3-layer GRU + attention window + MDN head
// B=32 T=512 U=64 V=60 H=400 K=10 M=20 IN=3
//
// Round 15b (resubmit; r13 GPU acquisition timed out). REVERT r14 (512-thr
// merge spilled registers: VGPR 164->128, FETCH 205->668MB, +61% time).
// Back to r13 structure (256-thr, 150 blocks), then REBALANCE: attention
// moves wholly into L0 (which already computes it for its own w input); L0
// slice-0 publishes w(t-1) to wring; L1 drops attention and stages w from
// wring like L2.
//  - L1 parent guard t+1 -> t+2 (needs w(t), published by L0 at step t+1)
//  - L0 adds wave-3 poll on group2 >= t-3 (wring slot-reuse protection)
//  - L0 epilogue: stage h0(T-1), compute w(T-1)+phi(T-1), out_phi, flag T+1
//  r13 kept: batched staging issue, wave-local attention, post-flag feature
//  stores, 3-acc MFMA chains, LDS-atomic w-scatter, s_sleep backoff.
// ---------------------------------------------------------------------------

typedef __attribute__((ext_vector_type(8))) short bf16x8;
typedef __attribute__((ext_vector_type(4))) float f32x4;
typedef unsigned short ushort_t;

namespace {
constexpr int B_ = 32, T_ = 512, U_ = 64, V_ = 60, H_ = 400, K_ = 10, M_ = 20;
constexpr int N_ = B_ * T_;          // 16384
constexpr int SEG = 416, FEAT_LD = 1248;
constexpr int NBLK = 150;
constexpr int SBL = 872;             // B-row stride in LDS (u16), 16B-aligned

// workspace layout (float indices)
constexpr size_t OFF_R0    = 0;                       // 4*32*400 u32 per ring
constexpr size_t OFF_R1    = 51200;
constexpr size_t OFF_R2    = 102400;
constexpr size_t OFF_WRING = 153600;                  // 4*32*60 f32
constexpr size_t OFF_BAR   = 161280;                  // 1088 uints
constexpr size_t ZERO_TOT  = OFF_BAR + 1088;
constexpr size_t OFF_FEATH = ZERO_TOT;                // N*1248 bf16
constexpr size_t OFF_FEATL = OFF_FEATH + (size_t)N_ * FEAT_LD / 2;
constexpr size_t OFF_WHH   = OFF_FEATL + (size_t)N_ * FEAT_LD / 2;  // 128*1248 bf16
constexpr size_t OFF_WHL   = OFF_WHH + (size_t)128 * FEAT_LD / 2;
constexpr size_t OFF_P     = OFF_WHL + (size_t)128 * FEAT_LD / 2;   // N*128 f32

// bar layout (uints): flags for group g (= L*2 + half) at [128 + 64*g + s],
// s = slice 0..24. 64-uint stride keeps each group on its own cache lines.
constexpr int BAR_FLAGS = 128;

// d_out layout (floats), reference return order
constexpr int DO_MEANS = 0;
constexpr int DO_STD   = B_ * T_ * M_ * 2;
constexpr int DO_LOGW  = DO_STD + B_ * T_ * M_;
constexpr int DO_CORR  = DO_LOGW + B_ * T_ * M_;
constexpr int DO_LAST  = DO_CORR + B_ * T_ * M_;
constexpr int DO_PHI   = DO_LAST + B_ * T_;
} // namespace

// ---------------------------------------------------------------------------
__device__ __forceinline__ float load_agent(const float* p) {
  return __hip_atomic_load(p, __ATOMIC_RELAXED, __HIP_MEMORY_SCOPE_AGENT);
}
__device__ __forceinline__ void store_agent(float* p, float v) {
  __hip_atomic_store(p, v, __ATOMIC_RELAXED, __HIP_MEMORY_SCOPE_AGENT);
}
__device__ __forceinline__ void store_agent_u32(unsigned* p, unsigned v) {
  __hip_atomic_store(p, v, __ATOMIC_RELAXED, __HIP_MEMORY_SCOPE_AGENT);
}
__device__ __forceinline__ unsigned load_agent_u32(const unsigned* p) {
  return __hip_atomic_load(p, __ATOMIC_RELAXED, __HIP_MEMORY_SCOPE_AGENT);
}
__device__ __forceinline__ unsigned long long load_agent_u64(const unsigned long long* p) {
  return __hip_atomic_load(p, __ATOMIC_RELAXED, __HIP_MEMORY_SCOPE_AGENT);
}
__device__ __forceinline__ ushort_t f2bf(float f) {
  union { float f; unsigned u; } x{f};
  unsigned r = x.u + 0x7FFFu + ((x.u >> 16) & 1u);
  return (ushort_t)(r >> 16);
}
__device__ __forceinline__ void split2(float f, ushort_t& h, ushort_t& l) {
  h = f2bf(f);
  union { unsigned u; float f; } c;
  c.u = ((unsigned)h) << 16;
  l = f2bf(f - c.f);
}
__device__ __forceinline__ float bfpair(ushort_t h, ushort_t l) {
  union { unsigned u; float f; } a, b;
  a.u = ((unsigned)h) << 16; b.u = ((unsigned)l) << 16;
  return a.f + b.f;
}
__device__ __forceinline__ float sigmoidf_(float x) {
  return 1.f / (1.f + __expf(-x));
}

// wave-parallel poll: lane i watches flags[i] (i<nf) until >= target.
__device__ __forceinline__ void wave_poll(const unsigned* flags, int nf, int target) {
  if (target <= 0) return;
  const int lane = threadIdx.x & 63;
  const unsigned* p = flags + (lane < nf ? lane : 0);
  int spins = 0;
  for (;;) {
    int v = (int)load_agent_u32(p);
    if (__all(lane >= nf || v >= target)) break;
    if (++spins > 3) __builtin_amdgcn_s_sleep(8);
    else             __builtin_amdgcn_s_sleep(1);
  }
}

// ---------------------------------------------------------------------------
// Staging split into issue (global loads into regs) and write (unpack -> LDS)
// so all rings' loads can be in flight together (one exposed LLC latency).
__device__ __forceinline__ void stage_issue(const unsigned* __restrict__ src,
                                            unsigned long long* v) {
  const int tid = threadIdx.x;
#pragma unroll
  for (int i = 0; i < 12; ++i)
    v[i] = load_agent_u64((const unsigned long long*)(src + (tid + i * 256) * 2));
  if (tid < 128)
    v[12] = load_agent_u64((const unsigned long long*)(src + (3072 + tid) * 2));
}
__device__ __forceinline__ void stage_write(const unsigned long long* v,
                                            ushort_t* __restrict__ BhB,
                                            ushort_t* __restrict__ BlB, int koff) {
  const int tid = threadIdx.x;
#pragma unroll
  for (int i = 0; i < 12; ++i) {
    int e = (tid + i * 256) * 2;
    int b = e / 400, k = e - b * 400;
    unsigned p0 = (unsigned)v[i], p1 = (unsigned)(v[i] >> 32);
    *(unsigned*)(BhB + b * SBL + koff + k) = (p0 >> 16) | (p1 & 0xFFFF0000u);
    *(unsigned*)(BlB + b * SBL + koff + k) = (p0 & 0xFFFFu) | (p1 << 16);
  }
  if (tid < 128) {
    int e = (3072 + tid) * 2;
    int b = e / 400, k = e - b * 400;
    unsigned p0 = (unsigned)v[12], p1 = (unsigned)(v[12] >> 32);
    *(unsigned*)(BhB + b * SBL + koff + k) = (p0 >> 16) | (p1 & 0xFFFF0000u);
    *(unsigned*)(BlB + b * SBL + koff + k) = (p0 & 0xFFFFu) | (p1 << 16);
  }
}

// ---------------------------------------------------------------------------
__global__ __launch_bounds__(256)
void zero_ws(float* __restrict__ p) {
  size_t i = (size_t)blockIdx.x * 256 + threadIdx.x;
  if (i < ZERO_TOT) p[i] = 0.f;
}

__global__ void zero_feat_pads(ushort_t* __restrict__ fh, ushort_t* __restrict__ fl) {
  int idx = blockIdx.x * 256 + threadIdx.x;
  if (idx >= N_ * 48) return;
  int n = idx / 48, r = idx % 48;
  size_t o = (size_t)n * FEAT_LD + (r / 16) * SEG + 400 + (r % 16);
  fh[o] = 0; fl[o] = 0;
}

__global__ void split_wh_kernel(const float* __restrict__ Wh,
                                ushort_t* __restrict__ hi, ushort_t* __restrict__ lo) {
  int idx = blockIdx.x * 256 + threadIdx.x;
  if (idx >= 128 * FEAT_LD) return;
  int m = idx / FEAT_LD, k = idx % FEAT_LD;
  int seg = k / SEG, off = k % SEG;
  float v = (m < 121 && off < 400) ? Wh[(size_t)m * 1200 + seg * 400 + off] : 0.f;
  ushort_t h, l; split2(v, h, l);
  hi[idx] = h; lo[idx] = l;
}

__global__ __launch_bounds__(256)
void gemm_split_kernel(const ushort_t* __restrict__ Ahi, const ushort_t* __restrict__ Alo,
                       const ushort_t* __restrict__ Bhi, const ushort_t* __restrict__ Blo,
                       const float* __restrict__ bias, float* __restrict__ C,
                       int mtiles, int ntiles, int ktiles, int strideA, int strideB,
                       int Mvalid, int ldc) {
  int wave = blockIdx.x * 4 + (threadIdx.x >> 6);
  if (wave >= mtiles * ntiles) return;
  int mt = wave / ntiles, nt = wave % ntiles;
  int lane = threadIdx.x & 63, l15 = lane & 15, quad = lane >> 4;
  size_t aoff = (size_t)(mt * 16 + l15) * strideA + quad * 8;
  size_t boff = (size_t)(nt * 16 + l15) * strideB + quad * 8;
  f32x4 a0 = {0.f, 0.f, 0.f, 0.f}, a1 = a0, a2 = a0;
  for (int kt = 0; kt < ktiles; ++kt) {
    bf16x8 ah = *(const bf16x8*)(Ahi + aoff + kt * 32);
    bf16x8 al = *(const bf16x8*)(Alo + aoff + kt * 32);
    bf16x8 bh = *(const bf16x8*)(Bhi + boff + kt * 32);
    bf16x8 bl = *(const bf16x8*)(Blo + boff + kt * 32);
    a0 = __builtin_amdgcn_mfma_f32_16x16x32_bf16(ah, bh, a0, 0, 0, 0);
    a1 = __builtin_amdgcn_mfma_f32_16x16x32_bf16(ah, bl, a1, 0, 0, 0);
    a2 = __builtin_amdgcn_mfma_f32_16x16x32_bf16(al, bh, a2, 0, 0, 0);
  }
  int n = nt * 16 + l15;
#pragma unroll
  for (int r = 0; r < 4; ++r) {
    int m = mt * 16 + quad * 4 + r;
    if (m < Mvalid) C[(size_t)n * ldc + m] = a0[r] + a1[r] + a2[r] + bias[m];
  }
}

// ---------------------------------------------------------------------------
// fused pipelined scan body (templated per layer)
template <int L>
__device__ __forceinline__ void scan_body(
    int slice, int bhalf,
    const float* __restrict__ x, const int* __restrict__ c,
    const float* __restrict__ Wih, const float* __restrict__ Whh,
    const float* __restrict__ bih, const float* __restrict__ bhh,
    const float* __restrict__ Ww, const float* __restrict__ bw,
    unsigned* __restrict__ ringS, const unsigned* __restrict__ ringP,
    const float* __restrict__ wring_c, float* __restrict__ wring_w,
    ushort_t* __restrict__ fh, ushort_t* __restrict__ fl,
    float* __restrict__ out_phi, unsigned* __restrict__ bar,
    ushort_t* Bh, ushort_t* Bl, float (*su)[65], float (*sp)[33],
    float (*skap)[10], unsigned char (*sc)[64], float (*sw)[60]) {
  constexpr int KT = (L == 0) ? 15 : 27;
  constexpr int CONST_K = (L == 0) ? 463 : 863;
  constexpr int XOFF = (L == 0) ? 460 : 860;
  constexpr int WOFF = (L == 0) ? 400 : 800;
  constexpr int IW = (L == 0) ? 63 : 463;
  const int tid = threadIdx.x;
  const int waveid = tid >> 6, lane = tid & 63;
  const int l15 = lane & 15, quad = lane >> 4;
  const int rt = waveid;                 // rowtile 0..3
  const int uu = l15 & 3, gate = l15 >> 2;   // 0=r 1=z 2=hn 3=inn
  const int J = slice * 16 + rt * 4 + uu;
  const int B0 = bhalf * 16;             // first global sample of this block

  // flag plumbing: own / parent / child / grandchild flag arrays
  unsigned* fOwn    = bar + BAR_FLAGS + 64 * (L * 2 + bhalf);
  unsigned* fParent = (L >= 1) ? bar + BAR_FLAGS + 64 * ((L - 1) * 2 + bhalf) : nullptr;
  unsigned* fChild  = (L <= 1) ? bar + BAR_FLAGS + 64 * ((L + 1) * 2 + bhalf) : nullptr;
  unsigned* fL2     = bar + BAR_FLAGS + 64 * (2 * 2 + bhalf);  // group2 (for L0)

  // ---- main A-fragments (split bf16), in registers for all 512 steps ----
  bf16x8 afh[KT], afl[KT];
#pragma unroll
  for (int kt = 0; kt < KT; ++kt) {
    union { bf16x8 v; ushort_t s[8]; } uh, ul;
#pragma unroll
    for (int j = 0; j < 8; ++j) {
      int k = kt * 32 + quad * 8 + j;
      float v = 0.f;
      if (k < 400) {
        if (gate == 0)      v = Whh[(size_t)J * 400 + k];
        else if (gate == 1) v = Whh[(size_t)(400 + J) * 400 + k];
        else if (gate == 2) v = Whh[(size_t)(800 + J) * 400 + k];
      } else if (k < CONST_K) {
        int col;
        if (L == 0) col = (k < 460) ? 3 + (k - 400) : (k - 460);
        else        col = (k < 800) ? 3 + (k - 400)
                        : (k < 860) ? 403 + (k - 800) : (k - 860);
        if (gate == 0)      v = Wih[(size_t)J * IW + col];
        else if (gate == 1) v = Wih[(size_t)(400 + J) * IW + col];
        else if (gate == 3) v = Wih[(size_t)(800 + J) * IW + col];
      } else if (k == CONST_K) {
        if (gate == 0)      v = bih[J] + bhh[J];
        else if (gate == 1) v = bih[400 + J] + bhh[400 + J];
        else if (gate == 2) v = bhh[800 + J];
        else                v = bih[800 + J];
      }
      ushort_t h, l; split2(v, h, l);
      uh.s[j] = h; ul.s[j] = l;
    }
    afh[kt] = uh.v; afl[kt] = ul.v;
  }

  // ---- attention p-fragments (L0 only now): waves 0/1 own 16 rows ----
  bf16x8 apfh[14], apfl[14];
  if constexpr (L == 0) {
    const int prow = (waveid < 2) ? (waveid * 16 + l15) : 32;
#pragma unroll
    for (int pk = 0; pk < 14; ++pk) {
      int kt = (pk < 13) ? pk : 14;
      union { bf16x8 v; ushort_t s[8]; } uh, ul;
#pragma unroll
      for (int j = 0; j < 8; ++j) {
        int k = kt * 32 + quad * 8 + j;
        float v = 0.f;
        if (prow < 30) {
          if (k < 400)           v = Ww[prow * 400 + k];
          else if (k == CONST_K) v = bw[prow];
        }
        ushort_t h, l; split2(v, h, l);
        uh.s[j] = h; ul.s[j] = l;
      }
      apfh[pk] = uh.v; apfl[pk] = ul.v;
    }
  }

  // ---- one-time LDS init ----
  for (int i = tid; i < 16 * SBL; i += 256) { Bh[i] = 0; Bl[i] = 0; }
  for (int i = tid; i < 160; i += 256) skap[i / 10][i % 10] = 0.f;
  if constexpr (L == 0) {
    for (int i = tid; i < 16 * 64; i += 256)
      sc[i >> 6][i & 63] = (unsigned char)c[(B0 + (i >> 6)) * U_ + (i & 63)];
  }
  __syncthreads();
  if (tid < 16) Bh[tid * SBL + CONST_K] = 0x3F80;  // bf16(1.0); lo stays 0
  __syncthreads();

  // ---- attention pass (L0 only): at call "t", input is staged h0(t-1);
  //      computes w(t-1) into LDS WOFF + publishes to wring slot (t-1)&3;
  //      t == T_ (epilogue) additionally writes out_phi = phi(T-1). ----
  auto attention_pass = [&](int t) {
    if (waveid < 2) {  // p-MFMA: rows waveid*16..+15 of 30, cols 16
      f32x4 a0 = {0.f, 0.f, 0.f, 0.f}, a1 = a0, a2 = a0;
      const int brow = l15 * SBL + quad * 8;
#pragma unroll
      for (int pk = 0; pk < 14; ++pk) {
        int kt = (pk < 13) ? pk : 14;
        bf16x8 bh8 = *(const bf16x8*)(Bh + brow + kt * 32);
        bf16x8 bl8 = *(const bf16x8*)(Bl + brow + kt * 32);
        a0 = __builtin_amdgcn_mfma_f32_16x16x32_bf16(apfh[pk], bh8, a0, 0, 0, 0);
        a1 = __builtin_amdgcn_mfma_f32_16x16x32_bf16(apfh[pk], bl8, a1, 0, 0, 0);
        a2 = __builtin_amdgcn_mfma_f32_16x16x32_bf16(apfl[pk], bh8, a2, 0, 0, 0);
      }
#pragma unroll
      for (int r = 0; r < 4; ++r)
        sp[l15][waveid * 16 + quad * 4 + r] = a0[r] + a1[r] + a2[r];
    }
    __syncthreads();
    // wave-local phases: wave owns samples b0..b0+3
    {
      const int b0 = waveid * 4;
      for (int i = lane; i < 120; i += 64) {           // exp(p)
        int b = b0 + i / 30, mm = i % 30;
        sp[b][mm] = __expf(sp[b][mm]);
      }
      if (lane < 40) {                                 // kappa += dk
        int b = b0 + lane / 10, k2 = lane % 10;
        skap[b][k2] += sp[b][20 + k2];
      }
      for (int i = lane; i < 240; i += 64)             // zero w accum
        sw[b0 + i / 60][i % 60] = 0.f;
      for (int i = lane; i < 260; i += 64) {           // phi
        int b = b0 + i / 65, u = i % 65;
        float s = 0.f;
#pragma unroll
        for (int k2 = 0; k2 < 10; ++k2) {
          float d = skap[b][k2] - (float)u;
          s = fmaf(sp[b][k2], __expf(-sp[b][10 + k2] * d * d), s);
        }
        su[b][u] = s;
      }
      for (int i = lane; i < 256; i += 64) {           // scatter phi -> w
        int b = b0 + (i >> 6), u = i & 63;
        atomicAdd(&sw[b][sc[b][u]], su[b][u]);
      }
      for (int i = lane; i < 240; i += 64) {           // write w into B + pub
        int b = b0 + i / 60, v = i % 60;
        float s = sw[b][v];
        ushort_t h, l2; split2(s, h, l2);
        Bh[b * SBL + WOFF + v] = h; Bl[b * SBL + WOFF + v] = l2;
        if (slice == 0)                                // publish w(t-1)
          store_agent(wring_w + (size_t)((t - 1) & 3) * 1920 + (B0 + b) * 60 + v, s);
      }
      if (t == T_ && slice == 0) {                     // phi termination
        for (int i = lane; i < 260; i += 64) {
          int b = b0 + i / 65, u = i % 65;
          out_phi[(B0 + b) * 65 + u] = su[b][u];
        }
      }
    }
    __syncthreads();
  };

  // ---- time loop: dataflow sync via wave-parallel flag polls ----
  for (int t = 0; t < T_; ++t) {
    if (waveid == 0)      wave_poll(fOwn, 25, t);                      // peers done t-1
    else if (waveid == 1) { if (L >= 1) wave_poll(fParent, 25, L == 1 ? t + 2 : t + 1); }
    else if (waveid == 2) { if (L <= 1) wave_poll(fChild, 25, t - 3); }
    else if (waveid == 3) { if (L == 0) wave_poll(fL2, 25, t - 3); }   // wring reuse
    __syncthreads();

    // -- staging ISSUE: all rings' loads in flight together --
    unsigned long long vS[13], vP[13];
    float wv[4] = {0.f, 0.f, 0.f, 0.f};
    float xv = 0.f;
    stage_issue(ringS + (size_t)((t + 3) & 3) * 12800 + B0 * 400, vS);
    if constexpr (L >= 1) {
      stage_issue(ringP + (size_t)(t & 3) * 12800 + B0 * 400, vP);
      const float* srcw = wring_c + (size_t)(t & 3) * 1920 + B0 * 60;
#pragma unroll
      for (int i = 0; i < 3; ++i) wv[i] = load_agent(srcw + tid + i * 256);
      if (tid < 192) wv[3] = load_agent(srcw + 768 + tid);
    }
    if (tid < 48) xv = x[((size_t)(B0 + tid / 3) * T_ + t) * 3 + (tid % 3)];

    // -- staging WRITE (consume in issue order) --
    stage_write(vS, Bh, Bl, 0);
    if constexpr (L >= 1) {
      stage_write(vP, Bh, Bl, 400);
#pragma unroll
      for (int i = 0; i < 3; ++i) {
        int idx = tid + i * 256;
        int b = idx / 60, v = idx - b * 60;
        ushort_t h, l; split2(wv[i], h, l);
        Bh[b * SBL + WOFF + v] = h; Bl[b * SBL + WOFF + v] = l;
      }
      if (tid < 192) {
        int idx = 768 + tid;
        int b = idx / 60, v = idx - b * 60;
        ushort_t h, l; split2(wv[3], h, l);
        Bh[b * SBL + WOFF + v] = h; Bl[b * SBL + WOFF + v] = l;
      }
    }
    if (tid < 48) {
      int b = tid / 3, xc = tid - b * 3;
      ushort_t h, l; split2(xv, h, l);
      Bh[b * SBL + XOFF + xc] = h; Bl[b * SBL + XOFF + xc] = l;
    }
    __syncthreads();

    // -- attention: L0 only, computes w(t-1) for own input + publishes --
    if constexpr (L == 0) {
      if (t > 0) attention_pass(t);
    }

    // -- main MFMA: rows = this wave's rowtile, cols = 16 samples --
    {
      f32x4 a0 = {0.f, 0.f, 0.f, 0.f}, a1 = a0, a2 = a0;
      const int brow = l15 * SBL + quad * 8;
#pragma unroll
      for (int kt = 0; kt < KT; ++kt) {
        bf16x8 bh8 = *(const bf16x8*)(Bh + brow + kt * 32);
        bf16x8 bl8 = *(const bf16x8*)(Bl + brow + kt * 32);
        a0 = __builtin_amdgcn_mfma_f32_16x16x32_bf16(afh[kt], bh8, a0, 0, 0, 0);
        a1 = __builtin_amdgcn_mfma_f32_16x16x32_bf16(afh[kt], bl8, a1, 0, 0, 0);
        a2 = __builtin_amdgcn_mfma_f32_16x16x32_bf16(afl[kt], bh8, a2, 0, 0, 0);
      }
#pragma unroll
      for (int r = 0; r < 4; ++r)
        su[l15][rt * 16 + quad * 4 + r] = a0[r] + a1[r] + a2[r];  // su as sdots
    }
    __syncthreads();

    // -- combine: 256 threads = 16 samples x 16 units (unit fastest) --
    ushort_t hh, hl;
    const int cb = tid >> 4, cu = tid & 15;
    {
      int urt = cu >> 2, u3 = cu & 3;
      float rr = sigmoidf_(su[cb][urt * 16 + 0 * 4 + u3]);
      float zz = sigmoidf_(su[cb][urt * 16 + 1 * 4 + u3]);
      float hn = su[cb][urt * 16 + 2 * 4 + u3];
      float inn = su[cb][urt * 16 + 3 * 4 + u3];
      int Jc = slice * 16 + cu;
      float hold = bfpair(Bh[cb * SBL + Jc], Bl[cb * SBL + Jc]);
      float hv = (1.f - zz) * tanhf(inn + rr * hn) + zz * hold;
      split2(hv, hh, hl);
      store_agent_u32(ringS + (size_t)(t & 3) * 12800 + (B0 + cb) * 400 + Jc,
                      ((unsigned)hh << 16) | (unsigned)hl);
    }

    // -- drain ring/wring stores, publish own flag (t+1) --
    __builtin_amdgcn_s_waitcnt(0);
    __syncthreads();
    if (tid == 0) store_agent_u32(fOwn + slice, (unsigned)(t + 1));

    // -- feature stores AFTER flag (gemm is kernel-boundary ordered) --
    {
      int n = (B0 + cb) * T_ + t;
      size_t fo = (size_t)n * FEAT_LD + L * SEG + (slice * 16 + cu);
      fh[fo] = hh; fl[fo] = hl;
    }
  }

  // ---- L0 epilogue: w(T-1) + phi(T-1) from h0(T-1); flag T+1 unblocks L1's
  //      final-step guard (fParent >= T+1). ----
  if constexpr (L == 0) {
    if (waveid == 0) wave_poll(fOwn, 25, T_);
    __syncthreads();
    unsigned long long vE[13];
    stage_issue(ringS + (size_t)((T_ + 3) & 3) * 12800 + B0 * 400, vE);
    stage_write(vE, Bh, Bl, 0);
    __syncthreads();
    attention_pass(T_);
    __builtin_amdgcn_s_waitcnt(0);
    __syncthreads();
    if (tid == 0) store_agent_u32(fOwn + slice, (unsigned)(T_ + 1));
  }
}

__global__ __launch_bounds__(256, 1)
void fused_scan(const float* __restrict__ x, const int* __restrict__ c,
                const float* Wih0, const float* Whh0, const float* bih0, const float* bhh0,
                const float* Wih1, const float* Whh1, const float* bih1, const float* bhh1,
                const float* Wih2, const float* Whh2, const float* bih2, const float* bhh2,
                const float* __restrict__ Ww, const float* __restrict__ bw,
                unsigned* ring0, unsigned* ring1, unsigned* ring2, float* wring,
                ushort_t* __restrict__ fh, ushort_t* __restrict__ fl,
                float* __restrict__ out_phi, unsigned* __restrict__ bar) {
  __shared__ ushort_t Bh[16 * SBL];
  __shared__ ushort_t Bl[16 * SBL];
  __shared__ float su[16][65];     // sdots (64 rows) UNION sphi (65)
  __shared__ float sp[16][33];     // attention p (exp'ed); rows 30,31 unused
  __shared__ float skap[16][10];
  __shared__ unsigned char sc[16][64];
  __shared__ float sw[16][60];     // w scatter accumulator

  const int bx = blockIdx.x;
  const int grpL = bx / 50, r = bx % 50;
  const int slice = r >> 1, bhalf = r & 1;

  if (grpL == 0)
    scan_body<0>(slice, bhalf, x, c, Wih0, Whh0, bih0, bhh0, Ww, bw,
                 ring0, nullptr, nullptr, wring, fh, fl, out_phi, bar,
                 Bh, Bl, su, sp, skap, sc, sw);
  else if (grpL == 1)
    scan_body<1>(slice, bhalf, x, c, Wih1, Whh1, bih1, bhh1, Ww, bw,
                 ring1, ring0, wring, nullptr, fh, fl, out_phi, bar,
                 Bh, Bl, su, sp, skap, sc, sw);
  else
    scan_body<2>(slice, bhalf, x, c, Wih2, Whh2, bih2, bhh2, Ww, bw,
                 ring2, ring1, wring, nullptr, fh, fl, out_phi, bar,
                 Bh, Bl, su, sp, skap, sc, sw);
}

// ---------------------------------------------------------------------------
__global__ __launch_bounds__(256)
void post_kernel(const float* __restrict__ p, float* __restrict__ dout) {
  int n = blockIdx.x * 256 + threadIdx.x;
  if (n >= N_) return;
  const float* r = p + (size_t)n * 128;
  dout[DO_LAST + n] = r[0];
  float mx = -1e30f;
  for (int m = 0; m < M_; ++m) mx = fmaxf(mx, r[1 + m]);
  float s = 0.f;
  for (int m = 0; m < M_; ++m) s += __expf(r[1 + m] - mx);
  float lse = mx + logf(s);
  for (int m = 0; m < M_; ++m) dout[DO_LOGW + (size_t)n * M_ + m] = r[1 + m] - lse;
  for (int i = 0; i < 2 * M_; ++i) dout[DO_MEANS + (size_t)n * 2 * M_ + i] = r[21 + i];
  for (int m = 0; m < M_; ++m) dout[DO_STD + (size_t)n * M_ + m] = __expf(r[61 + m]);
  for (int m = 0; m < M_; ++m) dout[DO_CORR + (size_t)n * M_ + m] = tanhf(r[81 + m]);
}

// ---------------------------------------------------------------------------
extern "C" void kernel_launch(void* const* d_in, const int* in_sizes, int n_in,
                              void* d_out, int out_size, void* d_ws, size_t ws_size,
                              hipStream_t stream) {
  const float* x    = (const float*)d_in[0];
  const int*   c    = (const int*)d_in[1];
  const float* Wih0 = (const float*)d_in[2];
  const float* Whh0 = (const float*)d_in[3];
  const float* bih0 = (const float*)d_in[4];
  const float* bhh0 = (const float*)d_in[5];
  const float* Wih1 = (const float*)d_in[6];
  const float* Whh1 = (const float*)d_in[7];
  const float* bih1 = (const float*)d_in[8];
  const float* bhh1 = (const float*)d_in[9];
  const float* Wih2 = (const float*)d_in[10];
  const float* Whh2 = (const float*)d_in[11];
  const float* bih2 = (const float*)d_in[12];
  const float* bhh2 = (const float*)d_in[13];
  const float* Ww   = (const float*)d_in[14];
  const float* bw   = (const float*)d_in[15];
  const float* Wh   = (const float*)d_in[16];
  const float* bh   = (const float*)d_in[17];
  (void)in_sizes; (void)n_in; (void)out_size; (void)ws_size;

  float* ws = (float*)d_ws;
  unsigned* ring0 = (unsigned*)(ws + OFF_R0);
  unsigned* ring1 = (unsigned*)(ws + OFF_R1);
  unsigned* ring2 = (unsigned*)(ws + OFF_R2);
  float*    wring = ws + OFF_WRING;
  unsigned* bar   = (unsigned*)(ws + OFF_BAR);
  ushort_t* fh    = (ushort_t*)(ws + OFF_FEATH);
  ushort_t* fl    = (ushort_t*)(ws + OFF_FEATL);
  ushort_t* whh_  = (ushort_t*)(ws + OFF_WHH);
  ushort_t* whl_  = (ushort_t*)(ws + OFF_WHL);
  float*    pbuf  = ws + OFF_P;
  float*    dout  = (float*)d_out;

  const dim3 blk(256);

  zero_ws<<<dim3((int)((ZERO_TOT + 255) / 256)), blk, 0, stream>>>(ws);
  zero_feat_pads<<<dim3((N_ * 48) / 256), blk, 0, stream>>>(fh, fl);
  split_wh_kernel<<<dim3((128 * FEAT_LD) / 256), blk, 0, stream>>>(Wh, whh_, whl_);

  fused_scan<<<dim3(NBLK), blk, 0, stream>>>(
      x, c, Wih0, Whh0, bih0, bhh0, Wih1, Whh1, bih1, bhh1,
      Wih2, Whh2, bih2, bhh2, Ww, bw,
      ring0, ring1, ring2, wring, fh, fl, dout + DO_PHI, bar);

  gemm_split_kernel<<<dim3(8 * (N_ / 16) / 4), blk, 0, stream>>>(
      whh_, whl_, fh, fl, bh, pbuf, 8, N_ / 16, FEAT_LD / 32,
      FEAT_LD, FEAT_LD, 121, 128);
  post_kernel<<<dim3(N_ / 256), blk, 0, stream>>>(pbuf, dout);
}

// Round 18
// 5282.810 us; speedup vs baseline: 2.2518x; 1.0732x over previous
//
#include <hip/hip_runtime.h>
#include <cmath>

// ---------------------------------------------------------------------------
// Graves handwriting synthesis: 3-layer GRU + attention window + MDN head
// B=32 T=512 U=64 V=60 H=400 K=10 M=20 IN=3
//
// Round 16 (4th submit; r15/r16/r17 GPU acquisition timed out): one cache
// line per flag (kill LLC line ping-pong).
//  r15b put all 25 slice flags of a group in 25 consecutive uints = 2 LLC
//  lines; 25 writers/step + ~60 polling waves hammer the same lines ->
//  store-store + store-probe serialization on every publish/observe hop.
//  Now FLAG_STRIDE=16 uints (64B): 1 writer per line, polls read 25
//  parallel lines. Protocol/guards identical to r15b (5670us, absmax .031):
//  L0 owns attention + publishes w to wring; L1 guard t+2; L0 wave-3 guard
//  group2 >= t-3; L0 epilogue w(T-1)/phi(T-1)/flag T+1.
// ---------------------------------------------------------------------------

typedef __attribute__((ext_vector_type(8))) short bf16x8;
typedef __attribute__((ext_vector_type(4))) float f32x4;
typedef unsigned short ushort_t;

namespace {
constexpr int B_ = 32, T_ = 512, U_ = 64, V_ = 60, H_ = 400, K_ = 10, M_ = 20;
constexpr int N_ = B_ * T_;          // 16384
constexpr int SEG = 416, FEAT_LD = 1248;
constexpr int NBLK = 150;
constexpr int SBL = 872;             // B-row stride in LDS (u16), 16B-aligned

// workspace layout (float indices)
constexpr size_t OFF_R0    = 0;                       // 4*32*400 u32 per ring
constexpr size_t OFF_R1    = 51200;
constexpr size_t OFF_R2    = 102400;
constexpr size_t OFF_WRING = 153600;                  // 4*32*60 f32
constexpr size_t OFF_BAR   = 161280;                  // 3200 uints now
constexpr size_t ZERO_TOT  = OFF_BAR + 3200;
constexpr size_t OFF_FEATH = ZERO_TOT;                // N*1248 bf16
constexpr size_t OFF_FEATL = OFF_FEATH + (size_t)N_ * FEAT_LD / 2;
constexpr size_t OFF_WHH   = OFF_FEATL + (size_t)N_ * FEAT_LD / 2;  // 128*1248 bf16
constexpr size_t OFF_WHL   = OFF_WHH + (size_t)128 * FEAT_LD / 2;
constexpr size_t OFF_P     = OFF_WHL + (size_t)128 * FEAT_LD / 2;   // N*128 f32

// bar layout (uints): group g (= L*2 + half) base at [128 + 512*g]; slice s
// flag at base + s*16 (one 64B line per flag -> 1 writer/line, no ping-pong).
constexpr int BAR_FLAGS = 128;
constexpr int FLAG_STRIDE = 16;
constexpr int GRP_STRIDE  = 512;

// d_out layout (floats), reference return order
constexpr int DO_MEANS = 0;
constexpr int DO_STD   = B_ * T_ * M_ * 2;
constexpr int DO_LOGW  = DO_STD + B_ * T_ * M_;
constexpr int DO_CORR  = DO_LOGW + B_ * T_ * M_;
constexpr int DO_LAST  = DO_CORR + B_ * T_ * M_;
constexpr int DO_PHI   = DO_LAST + B_ * T_;
} // namespace

// ---------------------------------------------------------------------------
__device__ __forceinline__ float load_agent(const float* p) {
  return __hip_atomic_load(p, __ATOMIC_RELAXED, __HIP_MEMORY_SCOPE_AGENT);
}
__device__ __forceinline__ void store_agent(float* p, float v) {
  __hip_atomic_store(p, v, __ATOMIC_RELAXED, __HIP_MEMORY_SCOPE_AGENT);
}
__device__ __forceinline__ void store_agent_u32(unsigned* p, unsigned v) {
  __hip_atomic_store(p, v, __ATOMIC_RELAXED, __HIP_MEMORY_SCOPE_AGENT);
}
__device__ __forceinline__ unsigned load_agent_u32(const unsigned* p) {
  return __hip_atomic_load(p, __ATOMIC_RELAXED, __HIP_MEMORY_SCOPE_AGENT);
}
__device__ __forceinline__ unsigned long long load_agent_u64(const unsigned long long* p) {
  return __hip_atomic_load(p, __ATOMIC_RELAXED, __HIP_MEMORY_SCOPE_AGENT);
}
__device__ __forceinline__ ushort_t f2bf(float f) {
  union { float f; unsigned u; } x{f};
  unsigned r = x.u + 0x7FFFu + ((x.u >> 16) & 1u);
  return (ushort_t)(r >> 16);
}
__device__ __forceinline__ void split2(float f, ushort_t& h, ushort_t& l) {
  h = f2bf(f);
  union { unsigned u; float f; } c;
  c.u = ((unsigned)h) << 16;
  l = f2bf(f - c.f);
}
__device__ __forceinline__ float bfpair(ushort_t h, ushort_t l) {
  union { unsigned u; float f; } a, b;
  a.u = ((unsigned)h) << 16; b.u = ((unsigned)l) << 16;
  return a.f + b.f;
}
__device__ __forceinline__ float sigmoidf_(float x) {
  return 1.f / (1.f + __expf(-x));
}

// wave-parallel poll: lane i watches flag line i (i<nf) until >= target.
__device__ __forceinline__ void wave_poll(const unsigned* flags, int nf, int target) {
  if (target <= 0) return;
  const int lane = threadIdx.x & 63;
  const unsigned* p = flags + (lane < nf ? lane : 0) * FLAG_STRIDE;
  int spins = 0;
  for (;;) {
    int v = (int)load_agent_u32(p);
    if (__all(lane >= nf || v >= target)) break;
    if (++spins > 3) __builtin_amdgcn_s_sleep(8);
    else             __builtin_amdgcn_s_sleep(1);
  }
}

// ---------------------------------------------------------------------------
// Staging split into issue (global loads into regs) and write (unpack -> LDS)
// so all rings' loads can be in flight together (one exposed LLC latency).
__device__ __forceinline__ void stage_issue(const unsigned* __restrict__ src,
                                            unsigned long long* v) {
  const int tid = threadIdx.x;
#pragma unroll
  for (int i = 0; i < 12; ++i)
    v[i] = load_agent_u64((const unsigned long long*)(src + (tid + i * 256) * 2));
  if (tid < 128)
    v[12] = load_agent_u64((const unsigned long long*)(src + (3072 + tid) * 2));
}
__device__ __forceinline__ void stage_write(const unsigned long long* v,
                                            ushort_t* __restrict__ BhB,
                                            ushort_t* __restrict__ BlB, int koff) {
  const int tid = threadIdx.x;
#pragma unroll
  for (int i = 0; i < 12; ++i) {
    int e = (tid + i * 256) * 2;
    int b = e / 400, k = e - b * 400;
    unsigned p0 = (unsigned)v[i], p1 = (unsigned)(v[i] >> 32);
    *(unsigned*)(BhB + b * SBL + koff + k) = (p0 >> 16) | (p1 & 0xFFFF0000u);
    *(unsigned*)(BlB + b * SBL + koff + k) = (p0 & 0xFFFFu) | (p1 << 16);
  }
  if (tid < 128) {
    int e = (3072 + tid) * 2;
    int b = e / 400, k = e - b * 400;
    unsigned p0 = (unsigned)v[12], p1 = (unsigned)(v[12] >> 32);
    *(unsigned*)(BhB + b * SBL + koff + k) = (p0 >> 16) | (p1 & 0xFFFF0000u);
    *(unsigned*)(BlB + b * SBL + koff + k) = (p0 & 0xFFFFu) | (p1 << 16);
  }
}

// ---------------------------------------------------------------------------
__global__ __launch_bounds__(256)
void zero_ws(float* __restrict__ p) {
  size_t i = (size_t)blockIdx.x * 256 + threadIdx.x;
  if (i < ZERO_TOT) p[i] = 0.f;
}

__global__ void zero_feat_pads(ushort_t* __restrict__ fh, ushort_t* __restrict__ fl) {
  int idx = blockIdx.x * 256 + threadIdx.x;
  if (idx >= N_ * 48) return;
  int n = idx / 48, r = idx % 48;
  size_t o = (size_t)n * FEAT_LD + (r / 16) * SEG + 400 + (r % 16);
  fh[o] = 0; fl[o] = 0;
}

__global__ void split_wh_kernel(const float* __restrict__ Wh,
                                ushort_t* __restrict__ hi, ushort_t* __restrict__ lo) {
  int idx = blockIdx.x * 256 + threadIdx.x;
  if (idx >= 128 * FEAT_LD) return;
  int m = idx / FEAT_LD, k = idx % FEAT_LD;
  int seg = k / SEG, off = k % SEG;
  float v = (m < 121 && off < 400) ? Wh[(size_t)m * 1200 + seg * 400 + off] : 0.f;
  ushort_t h, l; split2(v, h, l);
  hi[idx] = h; lo[idx] = l;
}

__global__ __launch_bounds__(256)
void gemm_split_kernel(const ushort_t* __restrict__ Ahi, const ushort_t* __restrict__ Alo,
                       const ushort_t* __restrict__ Bhi, const ushort_t* __restrict__ Blo,
                       const float* __restrict__ bias, float* __restrict__ C,
                       int mtiles, int ntiles, int ktiles, int strideA, int strideB,
                       int Mvalid, int ldc) {
  int wave = blockIdx.x * 4 + (threadIdx.x >> 6);
  if (wave >= mtiles * ntiles) return;
  int mt = wave / ntiles, nt = wave % ntiles;
  int lane = threadIdx.x & 63, l15 = lane & 15, quad = lane >> 4;
  size_t aoff = (size_t)(mt * 16 + l15) * strideA + quad * 8;
  size_t boff = (size_t)(nt * 16 + l15) * strideB + quad * 8;
  f32x4 a0 = {0.f, 0.f, 0.f, 0.f}, a1 = a0, a2 = a0;
  for (int kt = 0; kt < ktiles; ++kt) {
    bf16x8 ah = *(const bf16x8*)(Ahi + aoff + kt * 32);
    bf16x8 al = *(const bf16x8*)(Alo + aoff + kt * 32);
    bf16x8 bh = *(const bf16x8*)(Bhi + boff + kt * 32);
    bf16x8 bl = *(const bf16x8*)(Blo + boff + kt * 32);
    a0 = __builtin_amdgcn_mfma_f32_16x16x32_bf16(ah, bh, a0, 0, 0, 0);
    a1 = __builtin_amdgcn_mfma_f32_16x16x32_bf16(ah, bl, a1, 0, 0, 0);
    a2 = __builtin_amdgcn_mfma_f32_16x16x32_bf16(al, bh, a2, 0, 0, 0);
  }
  int n = nt * 16 + l15;
#pragma unroll
  for (int r = 0; r < 4; ++r) {
    int m = mt * 16 + quad * 4 + r;
    if (m < Mvalid) C[(size_t)n * ldc + m] = a0[r] + a1[r] + a2[r] + bias[m];
  }
}

// ---------------------------------------------------------------------------
// fused pipelined scan body (templated per layer)
template <int L>
__device__ __forceinline__ void scan_body(
    int slice, int bhalf,
    const float* __restrict__ x, const int* __restrict__ c,
    const float* __restrict__ Wih, const float* __restrict__ Whh,
    const float* __restrict__ bih, const float* __restrict__ bhh,
    const float* __restrict__ Ww, const float* __restrict__ bw,
    unsigned* __restrict__ ringS, const unsigned* __restrict__ ringP,
    const float* __restrict__ wring_c, float* __restrict__ wring_w,
    ushort_t* __restrict__ fh, ushort_t* __restrict__ fl,
    float* __restrict__ out_phi, unsigned* __restrict__ bar,
    ushort_t* Bh, ushort_t* Bl, float (*su)[65], float (*sp)[33],
    float (*skap)[10], unsigned char (*sc)[64], float (*sw)[60]) {
  constexpr int KT = (L == 0) ? 15 : 27;
  constexpr int CONST_K = (L == 0) ? 463 : 863;
  constexpr int XOFF = (L == 0) ? 460 : 860;
  constexpr int WOFF = (L == 0) ? 400 : 800;
  constexpr int IW = (L == 0) ? 63 : 463;
  const int tid = threadIdx.x;
  const int waveid = tid >> 6, lane = tid & 63;
  const int l15 = lane & 15, quad = lane >> 4;
  const int rt = waveid;                 // rowtile 0..3
  const int uu = l15 & 3, gate = l15 >> 2;   // 0=r 1=z 2=hn 3=inn
  const int J = slice * 16 + rt * 4 + uu;
  const int B0 = bhalf * 16;             // first global sample of this block

  // flag plumbing: own / parent / child / grandchild flag arrays
  unsigned* fOwn    = bar + BAR_FLAGS + GRP_STRIDE * (L * 2 + bhalf);
  unsigned* fParent = (L >= 1) ? bar + BAR_FLAGS + GRP_STRIDE * ((L - 1) * 2 + bhalf) : nullptr;
  unsigned* fChild  = (L <= 1) ? bar + BAR_FLAGS + GRP_STRIDE * ((L + 1) * 2 + bhalf) : nullptr;
  unsigned* fL2     = bar + BAR_FLAGS + GRP_STRIDE * (2 * 2 + bhalf);  // group2 (for L0)

  // ---- main A-fragments (split bf16), in registers for all 512 steps ----
  bf16x8 afh[KT], afl[KT];
#pragma unroll
  for (int kt = 0; kt < KT; ++kt) {
    union { bf16x8 v; ushort_t s[8]; } uh, ul;
#pragma unroll
    for (int j = 0; j < 8; ++j) {
      int k = kt * 32 + quad * 8 + j;
      float v = 0.f;
      if (k < 400) {
        if (gate == 0)      v = Whh[(size_t)J * 400 + k];
        else if (gate == 1) v = Whh[(size_t)(400 + J) * 400 + k];
        else if (gate == 2) v = Whh[(size_t)(800 + J) * 400 + k];
      } else if (k < CONST_K) {
        int col;
        if (L == 0) col = (k < 460) ? 3 + (k - 400) : (k - 460);
        else        col = (k < 800) ? 3 + (k - 400)
                        : (k < 860) ? 403 + (k - 800) : (k - 860);
        if (gate == 0)      v = Wih[(size_t)J * IW + col];
        else if (gate == 1) v = Wih[(size_t)(400 + J) * IW + col];
        else if (gate == 3) v = Wih[(size_t)(800 + J) * IW + col];
      } else if (k == CONST_K) {
        if (gate == 0)      v = bih[J] + bhh[J];
        else if (gate == 1) v = bih[400 + J] + bhh[400 + J];
        else if (gate == 2) v = bhh[800 + J];
        else                v = bih[800 + J];
      }
      ushort_t h, l; split2(v, h, l);
      uh.s[j] = h; ul.s[j] = l;
    }
    afh[kt] = uh.v; afl[kt] = ul.v;
  }

  // ---- attention p-fragments (L0 only now): waves 0/1 own 16 rows ----
  bf16x8 apfh[14], apfl[14];
  if constexpr (L == 0) {
    const int prow = (waveid < 2) ? (waveid * 16 + l15) : 32;
#pragma unroll
    for (int pk = 0; pk < 14; ++pk) {
      int kt = (pk < 13) ? pk : 14;
      union { bf16x8 v; ushort_t s[8]; } uh, ul;
#pragma unroll
      for (int j = 0; j < 8; ++j) {
        int k = kt * 32 + quad * 8 + j;
        float v = 0.f;
        if (prow < 30) {
          if (k < 400)           v = Ww[prow * 400 + k];
          else if (k == CONST_K) v = bw[prow];
        }
        ushort_t h, l; split2(v, h, l);
        uh.s[j] = h; ul.s[j] = l;
      }
      apfh[pk] = uh.v; apfl[pk] = ul.v;
    }
  }

  // ---- one-time LDS init ----
  for (int i = tid; i < 16 * SBL; i += 256) { Bh[i] = 0; Bl[i] = 0; }
  for (int i = tid; i < 160; i += 256) skap[i / 10][i % 10] = 0.f;
  if constexpr (L == 0) {
    for (int i = tid; i < 16 * 64; i += 256)
      sc[i >> 6][i & 63] = (unsigned char)c[(B0 + (i >> 6)) * U_ + (i & 63)];
  }
  __syncthreads();
  if (tid < 16) Bh[tid * SBL + CONST_K] = 0x3F80;  // bf16(1.0); lo stays 0
  __syncthreads();

  // ---- attention pass (L0 only): at call "t", input is staged h0(t-1);
  //      computes w(t-1) into LDS WOFF + publishes to wring slot (t-1)&3;
  //      t == T_ (epilogue) additionally writes out_phi = phi(T-1). ----
  auto attention_pass = [&](int t) {
    if (waveid < 2) {  // p-MFMA: rows waveid*16..+15 of 30, cols 16
      f32x4 a0 = {0.f, 0.f, 0.f, 0.f}, a1 = a0, a2 = a0;
      const int brow = l15 * SBL + quad * 8;
#pragma unroll
      for (int pk = 0; pk < 14; ++pk) {
        int kt = (pk < 13) ? pk : 14;
        bf16x8 bh8 = *(const bf16x8*)(Bh + brow + kt * 32);
        bf16x8 bl8 = *(const bf16x8*)(Bl + brow + kt * 32);
        a0 = __builtin_amdgcn_mfma_f32_16x16x32_bf16(apfh[pk], bh8, a0, 0, 0, 0);
        a1 = __builtin_amdgcn_mfma_f32_16x16x32_bf16(apfh[pk], bl8, a1, 0, 0, 0);
        a2 = __builtin_amdgcn_mfma_f32_16x16x32_bf16(apfl[pk], bh8, a2, 0, 0, 0);
      }
#pragma unroll
      for (int r = 0; r < 4; ++r)
        sp[l15][waveid * 16 + quad * 4 + r] = a0[r] + a1[r] + a2[r];
    }
    __syncthreads();
    // wave-local phases: wave owns samples b0..b0+3
    {
      const int b0 = waveid * 4;
      for (int i = lane; i < 120; i += 64) {           // exp(p)
        int b = b0 + i / 30, mm = i % 30;
        sp[b][mm] = __expf(sp[b][mm]);
      }
      if (lane < 40) {                                 // kappa += dk
        int b = b0 + lane / 10, k2 = lane % 10;
        skap[b][k2] += sp[b][20 + k2];
      }
      for (int i = lane; i < 240; i += 64)             // zero w accum
        sw[b0 + i / 60][i % 60] = 0.f;
      for (int i = lane; i < 260; i += 64) {           // phi
        int b = b0 + i / 65, u = i % 65;
        float s = 0.f;
#pragma unroll
        for (int k2 = 0; k2 < 10; ++k2) {
          float d = skap[b][k2] - (float)u;
          s = fmaf(sp[b][k2], __expf(-sp[b][10 + k2] * d * d), s);
        }
        su[b][u] = s;
      }
      for (int i = lane; i < 256; i += 64) {           // scatter phi -> w
        int b = b0 + (i >> 6), u = i & 63;
        atomicAdd(&sw[b][sc[b][u]], su[b][u]);
      }
      for (int i = lane; i < 240; i += 64) {           // write w into B + pub
        int b = b0 + i / 60, v = i % 60;
        float s = sw[b][v];
        ushort_t h, l2; split2(s, h, l2);
        Bh[b * SBL + WOFF + v] = h; Bl[b * SBL + WOFF + v] = l2;
        if (slice == 0)                                // publish w(t-1)
          store_agent(wring_w + (size_t)((t - 1) & 3) * 1920 + (B0 + b) * 60 + v, s);
      }
      if (t == T_ && slice == 0) {                     // phi termination
        for (int i = lane; i < 260; i += 64) {
          int b = b0 + i / 65, u = i % 65;
          out_phi[(B0 + b) * 65 + u] = su[b][u];
        }
      }
    }
    __syncthreads();
  };

  // ---- time loop: dataflow sync via wave-parallel flag polls ----
  for (int t = 0; t < T_; ++t) {
    if (waveid == 0)      wave_poll(fOwn, 25, t);                      // peers done t-1
    else if (waveid == 1) { if (L >= 1) wave_poll(fParent, 25, L == 1 ? t + 2 : t + 1); }
    else if (waveid == 2) { if (L <= 1) wave_poll(fChild, 25, t - 3); }
    else if (waveid == 3) { if (L == 0) wave_poll(fL2, 25, t - 3); }   // wring reuse
    __syncthreads();

    // -- staging ISSUE: all rings' loads in flight together --
    unsigned long long vS[13], vP[13];
    float wv[4] = {0.f, 0.f, 0.f, 0.f};
    float xv = 0.f;
    stage_issue(ringS + (size_t)((t + 3) & 3) * 12800 + B0 * 400, vS);
    if constexpr (L >= 1) {
      stage_issue(ringP + (size_t)(t & 3) * 12800 + B0 * 400, vP);
      const float* srcw = wring_c + (size_t)(t & 3) * 1920 + B0 * 60;
#pragma unroll
      for (int i = 0; i < 3; ++i) wv[i] = load_agent(srcw + tid + i * 256);
      if (tid < 192) wv[3] = load_agent(srcw + 768 + tid);
    }
    if (tid < 48) xv = x[((size_t)(B0 + tid / 3) * T_ + t) * 3 + (tid % 3)];

    // -- staging WRITE (consume in issue order) --
    stage_write(vS, Bh, Bl, 0);
    if constexpr (L >= 1) {
      stage_write(vP, Bh, Bl, 400);
#pragma unroll
      for (int i = 0; i < 3; ++i) {
        int idx = tid + i * 256;
        int b = idx / 60, v = idx - b * 60;
        ushort_t h, l; split2(wv[i], h, l);
        Bh[b * SBL + WOFF + v] = h; Bl[b * SBL + WOFF + v] = l;
      }
      if (tid < 192) {
        int idx = 768 + tid;
        int b = idx / 60, v = idx - b * 60;
        ushort_t h, l; split2(wv[3], h, l);
        Bh[b * SBL + WOFF + v] = h; Bl[b * SBL + WOFF + v] = l;
      }
    }
    if (tid < 48) {
      int b = tid / 3, xc = tid - b * 3;
      ushort_t h, l; split2(xv, h, l);
      Bh[b * SBL + XOFF + xc] = h; Bl[b * SBL + XOFF + xc] = l;
    }
    __syncthreads();

    // -- attention: L0 only, computes w(t-1) for own input + publishes --
    if constexpr (L == 0) {
      if (t > 0) attention_pass(t);
    }

    // -- main MFMA: rows = this wave's rowtile, cols = 16 samples --
    {
      f32x4 a0 = {0.f, 0.f, 0.f, 0.f}, a1 = a0, a2 = a0;
      const int brow = l15 * SBL + quad * 8;
#pragma unroll
      for (int kt = 0; kt < KT; ++kt) {
        bf16x8 bh8 = *(const bf16x8*)(Bh + brow + kt * 32);
        bf16x8 bl8 = *(const bf16x8*)(Bl + brow + kt * 32);
        a0 = __builtin_amdgcn_mfma_f32_16x16x32_bf16(afh[kt], bh8, a0, 0, 0, 0);
        a1 = __builtin_amdgcn_mfma_f32_16x16x32_bf16(afh[kt], bl8, a1, 0, 0, 0);
        a2 = __builtin_amdgcn_mfma_f32_16x16x32_bf16(afl[kt], bh8, a2, 0, 0, 0);
      }
#pragma unroll
      for (int r = 0; r < 4; ++r)
        su[l15][rt * 16 + quad * 4 + r] = a0[r] + a1[r] + a2[r];  // su as sdots
    }
    __syncthreads();

    // -- combine: 256 threads = 16 samples x 16 units (unit fastest) --
    ushort_t hh, hl;
    const int cb = tid >> 4, cu = tid & 15;
    {
      int urt = cu >> 2, u3 = cu & 3;
      float rr = sigmoidf_(su[cb][urt * 16 + 0 * 4 + u3]);
      float zz = sigmoidf_(su[cb][urt * 16 + 1 * 4 + u3]);
      float hn = su[cb][urt * 16 + 2 * 4 + u3];
      float inn = su[cb][urt * 16 + 3 * 4 + u3];
      int Jc = slice * 16 + cu;
      float hold = bfpair(Bh[cb * SBL + Jc], Bl[cb * SBL + Jc]);
      float hv = (1.f - zz) * tanhf(inn + rr * hn) + zz * hold;
      split2(hv, hh, hl);
      store_agent_u32(ringS + (size_t)(t & 3) * 12800 + (B0 + cb) * 400 + Jc,
                      ((unsigned)hh << 16) | (unsigned)hl);
    }

    // -- drain ring/wring stores, publish own flag (t+1) --
    __builtin_amdgcn_s_waitcnt(0);
    __syncthreads();
    if (tid == 0) store_agent_u32(fOwn + slice * FLAG_STRIDE, (unsigned)(t + 1));

    // -- feature stores AFTER flag (gemm is kernel-boundary ordered) --
    {
      int n = (B0 + cb) * T_ + t;
      size_t fo = (size_t)n * FEAT_LD + L * SEG + (slice * 16 + cu);
      fh[fo] = hh; fl[fo] = hl;
    }
  }

  // ---- L0 epilogue: w(T-1) + phi(T-1) from h0(T-1); flag T+1 unblocks L1's
  //      final-step guard (fParent >= T+1). ----
  if constexpr (L == 0) {
    if (waveid == 0) wave_poll(fOwn, 25, T_);
    __syncthreads();
    unsigned long long vE[13];
    stage_issue(ringS + (size_t)((T_ + 3) & 3) * 12800 + B0 * 400, vE);
    stage_write(vE, Bh, Bl, 0);
    __syncthreads();
    attention_pass(T_);
    __builtin_amdgcn_s_waitcnt(0);
    __syncthreads();
    if (tid == 0) store_agent_u32(fOwn + slice * FLAG_STRIDE, (unsigned)(T_ + 1));
  }
}

__global__ __launch_bounds__(256, 1)
void fused_scan(const float* __restrict__ x, const int* __restrict__ c,
                const float* Wih0, const float* Whh0, const float* bih0, const float* bhh0,
                const float* Wih1, const float* Whh1, const float* bih1, const float* bhh1,
                const float* Wih2, const float* Whh2, const float* bih2, const float* bhh2,
                const float* __restrict__ Ww, const float* __restrict__ bw,
                unsigned* ring0, unsigned* ring1, unsigned* ring2, float* wring,
                ushort_t* __restrict__ fh, ushort_t* __restrict__ fl,
                float* __restrict__ out_phi, unsigned* __restrict__ bar) {
  __shared__ ushort_t Bh[16 * SBL];
  __shared__ ushort_t Bl[16 * SBL];
  __shared__ float su[16][65];     // sdots (64 rows) UNION sphi (65)
  __shared__ float sp[16][33];     // attention p (exp'ed); rows 30,31 unused
  __shared__ float skap[16][10];
  __shared__ unsigned char sc[16][64];
  __shared__ float sw[16][60];     // w scatter accumulator

  const int bx = blockIdx.x;
  const int grpL = bx / 50, r = bx % 50;
  const int slice = r >> 1, bhalf = r & 1;

  if (grpL == 0)
    scan_body<0>(slice, bhalf, x, c, Wih0, Whh0, bih0, bhh0, Ww, bw,
                 ring0, nullptr, nullptr, wring, fh, fl, out_phi, bar,
                 Bh, Bl, su, sp, skap, sc, sw);
  else if (grpL == 1)
    scan_body<1>(slice, bhalf, x, c, Wih1, Whh1, bih1, bhh1, Ww, bw,
                 ring1, ring0, wring, nullptr, fh, fl, out_phi, bar,
                 Bh, Bl, su, sp, skap, sc, sw);
  else
    scan_body<2>(slice, bhalf, x, c, Wih2, Whh2, bih2, bhh2, Ww, bw,
                 ring2, ring1, wring, nullptr, fh, fl, out_phi, bar,
                 Bh, Bl, su, sp, skap, sc, sw);
}

// ---------------------------------------------------------------------------
__global__ __launch_bounds__(256)
void post_kernel(const float* __restrict__ p, float* __restrict__ dout) {
  int n = blockIdx.x * 256 + threadIdx.x;
  if (n >= N_) return;
  const float* r = p + (size_t)n * 128;
  dout[DO_LAST + n] = r[0];
  float mx = -1e30f;
  for (int m = 0; m < M_; ++m) mx = fmaxf(mx, r[1 + m]);
  float s = 0.f;
  for (int m = 0; m < M_; ++m) s += __expf(r[1 + m] - mx);
  float lse = mx + logf(s);
  for (int m = 0; m < M_; ++m) dout[DO_LOGW + (size_t)n * M_ + m] = r[1 + m] - lse;
  for (int i = 0; i < 2 * M_; ++i) dout[DO_MEANS + (size_t)n * 2 * M_ + i] = r[21 + i];
  for (int m = 0; m < M_; ++m) dout[DO_STD + (size_t)n * M_ + m] = __expf(r[61 + m]);
  for (int m = 0; m < M_; ++m) dout[DO_CORR + (size_t)n * M_ + m] = tanhf(r[81 + m]);
}

// ---------------------------------------------------------------------------
extern "C" void kernel_launch(void* const* d_in, const int* in_sizes, int n_in,
                              void* d_out, int out_size, void* d_ws, size_t ws_size,
                              hipStream_t stream) {
  const float* x    = (const float*)d_in[0];
  const int*   c    = (const int*)d_in[1];
  const float* Wih0 = (const float*)d_in[2];
  const float* Whh0 = (const float*)d_in[3];
  const float* bih0 = (const float*)d_in[4];
  const float* bhh0 = (const float*)d_in[5];
  const float* Wih1 = (const float*)d_in[6];
  const float* Whh1 = (const float*)d_in[7];
  const float* bih1 = (const float*)d_in[8];
  const float* bhh1 = (const float*)d_in[9];
  const float* Wih2 = (const float*)d_in[10];
  const float* Whh2 = (const float*)d_in[11];
  const float* bih2 = (const float*)d_in[12];
  const float* bhh2 = (const float*)d_in[13];
  const float* Ww   = (const float*)d_in[14];
  const float* bw   = (const float*)d_in[15];
  const float* Wh   = (const float*)d_in[16];
  const float* bh   = (const float*)d_in[17];
  (void)in_sizes; (void)n_in; (void)out_size; (void)ws_size;

  float* ws = (float*)d_ws;
  unsigned* ring0 = (unsigned*)(ws + OFF_R0);
  unsigned* ring1 = (unsigned*)(ws + OFF_R1);
  unsigned* ring2 = (unsigned*)(ws + OFF_R2);
  float*    wring = ws + OFF_WRING;
  unsigned* bar   = (unsigned*)(ws + OFF_BAR);
  ushort_t* fh    = (ushort_t*)(ws + OFF_FEATH);
  ushort_t* fl    = (ushort_t*)(ws + OFF_FEATL);
  ushort_t* whh_  = (ushort_t*)(ws + OFF_WHH);
  ushort_t* whl_  = (ushort_t*)(ws + OFF_WHL);
  float*    pbuf  = ws + OFF_P;
  float*    dout  = (float*)d_out;

  const dim3 blk(256);

  zero_ws<<<dim3((int)((ZERO_TOT + 255) / 256)), blk, 0, stream>>>(ws);
  zero_feat_pads<<<dim3((N_ * 48) / 256), blk, 0, stream>>>(fh, fl);
  split_wh_kernel<<<dim3((128 * FEAT_LD) / 256), blk, 0, stream>>>(Wh, whh_, whl_);

  fused_scan<<<dim3(NBLK), blk, 0, stream>>>(
      x, c, Wih0, Whh0, bih0, bhh0, Wih1, Whh1, bih1, bhh1,
      Wih2, Whh2, bih2, bhh2, Ww, bw,
      ring0, ring1, ring2, wring, fh, fl, dout + DO_PHI, bar);

  gemm_split_kernel<<<dim3(8 * (N_ / 16) / 4), blk, 0, stream>>>(
      whh_, whl_, fh, fl, bh, pbuf, 8, N_ / 16, FEAT_LD / 32,
      FEAT_LD, FEAT_LD, 121, 128);
  post_kernel<<<dim3(N_ / 256), blk, 0, stream>>>(pbuf, dout);
}